// Round 3
// baseline (48.357 us; speedup 1.0000x reference)
//
#include <hip/hip_runtime.h>
#include <math.h>

// SpectralContrastPrior: per (b, band, t) column, mean of top-3 and bottom-3
// over the band's frequency rows (170 for bands 0..4, 175 for band 5).
// Input:  power_spec (32, 1025, 2000) f32
// Output: peaks (32, 6, 2000) f32 followed by valleys (32, 6, 2000) f32, flat.
//
// k = 3 for all bands -> running top-3/bot-3 insert network, no sort.
// Memory-bound streaming: 262 MB read once, 3 MB write.
// R3: split each column across 2 adjacent lanes (row halves) -> 2x waves/CU
// (23.4 vs 11.7) for deeper memory-level parallelism; merge via shfl_xor(1).

constexpr int B_    = 32;
constexpr int NF    = 1025;
constexpr int T_    = 2000;
constexpr int NB    = 6;
constexpr int BAND  = NF / NB;   // 170
constexpr int VEC   = 2;         // float2 per thread along t
constexpr int TG    = T_ / VEC;  // 1000
constexpr int SPLIT = 2;         // row-halves per column

// Maintain sorted top-3 (t0 >= t1 >= t2): 5 min/max ops.
__device__ __forceinline__ void ins_top(float& t0, float& t1, float& t2, float x) {
    float lo0 = fminf(t0, x);
    t0 = fmaxf(t0, x);
    float lo1 = fminf(t1, lo0);
    t1 = fmaxf(t1, lo0);
    t2 = fmaxf(t2, lo1);
}
// Maintain sorted bottom-3 (b0 <= b1 <= b2): 5 min/max ops.
__device__ __forceinline__ void ins_bot(float& b0, float& b1, float& b2, float x) {
    float hi0 = fmaxf(b0, x);
    b0 = fminf(b0, x);
    float hi1 = fmaxf(b1, hi0);
    b1 = fminf(b1, hi0);
    b2 = fminf(b2, hi1);
}

struct Acc3 {
    float x0, x1, x2;   // top-3
    float n0, n1, n2;   // bottom-3
    __device__ __forceinline__ void init() {
        x0 = x1 = x2 = -INFINITY;
        n0 = n1 = n2 =  INFINITY;
    }
    __device__ __forceinline__ void push(float v) {
        ins_top(x0, x1, x2, v);
        ins_bot(n0, n1, n2, v);
    }
    // Fold partner lane's triples in (partner differs in lane bit 0).
    __device__ __forceinline__ void merge_xor1() {
        float px0 = __shfl_xor(x0, 1), px1 = __shfl_xor(x1, 1), px2 = __shfl_xor(x2, 1);
        float pn0 = __shfl_xor(n0, 1), pn1 = __shfl_xor(n1, 1), pn2 = __shfl_xor(n2, 1);
        ins_top(x0, x1, x2, px0); ins_top(x0, x1, x2, px1); ins_top(x0, x1, x2, px2);
        ins_bot(n0, n1, n2, pn0); ins_bot(n0, n1, n2, pn1); ins_bot(n0, n1, n2, pn2);
    }
    __device__ __forceinline__ float peak()   const { return (x0 + x1 + x2) * (1.0f / 3.0f); }
    __device__ __forceinline__ float valley() const { return (n0 + n1 + n2) * (1.0f / 3.0f); }
};

__global__ __launch_bounds__(256) void scp_kernel(const float* __restrict__ in,
                                                  float* __restrict__ out) {
    int idx = blockIdx.x * blockDim.x + threadIdx.x;
    if (idx >= B_ * NB * TG * SPLIT) return;

    int s    = idx & 1;           // row-half (lane bit 0 -> partner is lane^1)
    int cid  = idx >> 1;
    int tg   = cid % TG;          // even/odd lanes each cover consecutive tg
    int rest = cid / TG;
    int band = rest % NB;
    int b    = rest / NB;

    int row0  = band * BAND;
    int nrows = (band == NB - 1) ? (NF - row0) : BAND;   // 175 or 170
    int h0    = nrows / 2;                               // 85 or 87
    int rlo   = s ? h0 : 0;
    int rhi   = s ? nrows : h0;

    const float* p = in + (size_t)b * NF * T_ + (size_t)(row0 + rlo) * T_
                        + (size_t)tg * VEC;
    int myrows = rhi - rlo;       // 85/85 or 87/88

    Acc3 a0, a1;
    a0.init(); a1.init();

    #pragma unroll 5
    for (int r = 0; r < myrows; ++r) {
        float2 v = *reinterpret_cast<const float2*>(p + (size_t)r * T_);
        a0.push(v.x);
        a1.push(v.y);
    }

    // Merge the two row-halves (both partners end with identical triples).
    a0.merge_xor1();
    a1.merge_xor1();

    size_t o    = (size_t)b * NB * T_ + (size_t)band * T_ + (size_t)tg * VEC;
    size_t voff = (size_t)B_ * NB * T_;

    // Even lanes store peaks, odd lanes store valleys: all 64 lanes store 8 B,
    // each half-wave's addresses contiguous (256 B segments).
    if (s == 0) {
        *reinterpret_cast<float2*>(out + o) = make_float2(a0.peak(), a1.peak());
    } else {
        *reinterpret_cast<float2*>(out + voff + o) = make_float2(a0.valley(), a1.valley());
    }
}

extern "C" void kernel_launch(void* const* d_in, const int* in_sizes, int n_in,
                              void* d_out, int out_size, void* d_ws, size_t ws_size,
                              hipStream_t stream) {
    const float* in = (const float*)d_in[0];
    float* out = (float*)d_out;

    int total = B_ * NB * TG * SPLIT;         // 384000 threads
    int block = 256;
    int grid  = (total + block - 1) / block;  // 1500 blocks, ~23.4 waves/CU
    scp_kernel<<<grid, block, 0, stream>>>(in, out);
}

// Round 4
// 45.848 us; speedup vs baseline: 1.0547x; 1.0547x over previous
//
#include <hip/hip_runtime.h>
#include <math.h>

// SpectralContrastPrior: per (b, band, t) column, mean of top-3 and bottom-3
// over the band's frequency rows (170 for bands 0..4, 175 for band 5).
// Input:  power_spec (32, 1025, 2000) f32
// Output: peaks (32, 6, 2000) f32 followed by valleys (32, 6, 2000) f32, flat.
//
// k = int(170*0.02) = int(175*0.02) = 3 for all bands -> running top-3/bot-3
// via a 5-op min/max insert network; no sort needed. Memory-bound streaming:
// 262 MB read once, 3 MB write. Best config (R1): float2/thread, 192k threads,
// 750 blocks x 256, ~12 waves/CU. Measured 46.9 us = 5.65 TB/s ~= 90% of the
// 6.29 TB/s achievable read BW -> streaming roofline. R2 (float4, 6 waves/CU)
// and R3 (2-way row split, 23 waves/CU) both measured slightly worse.

constexpr int B_   = 32;
constexpr int NF   = 1025;
constexpr int T_   = 2000;
constexpr int NB   = 6;
constexpr int BAND = NF / NB;   // 170
constexpr int VEC  = 2;         // float2 per thread along t
constexpr int TG   = T_ / VEC;  // 1000

// Maintain sorted top-3 (t0 >= t1 >= t2): 5 min/max ops.
__device__ __forceinline__ void ins_top(float& t0, float& t1, float& t2, float x) {
    float lo0 = fminf(t0, x);
    t0 = fmaxf(t0, x);
    float lo1 = fminf(t1, lo0);
    t1 = fmaxf(t1, lo0);
    t2 = fmaxf(t2, lo1);
}
// Maintain sorted bottom-3 (b0 <= b1 <= b2): 5 min/max ops.
__device__ __forceinline__ void ins_bot(float& b0, float& b1, float& b2, float x) {
    float hi0 = fmaxf(b0, x);
    b0 = fminf(b0, x);
    float hi1 = fmaxf(b1, hi0);
    b1 = fminf(b1, hi0);
    b2 = fminf(b2, hi1);
}

__global__ __launch_bounds__(256) void scp_kernel(const float* __restrict__ in,
                                                  float* __restrict__ out) {
    int idx = blockIdx.x * blockDim.x + threadIdx.x;
    if (idx >= B_ * NB * TG) return;

    int tg   = idx % TG;          // consecutive lanes -> consecutive t: coalesced
    int rest = idx / TG;
    int band = rest % NB;
    int b    = rest / NB;

    int row0  = band * BAND;
    int nrows = (band == NB - 1) ? (NF - row0) : BAND;   // 175 or 170

    const float* p = in + (size_t)b * NF * T_ + (size_t)row0 * T_ + (size_t)tg * VEC;

    // Two t-columns per thread (x / y of the float2).
    float ax0 = -INFINITY, ax1 = -INFINITY, ax2 = -INFINITY;
    float an0 =  INFINITY, an1 =  INFINITY, an2 =  INFINITY;
    float bx0 = -INFINITY, bx1 = -INFINITY, bx2 = -INFINITY;
    float bn0 =  INFINITY, bn1 =  INFINITY, bn2 =  INFINITY;

    #pragma unroll 5   // 170 % 5 == 0 and 175 % 5 == 0
    for (int r = 0; r < nrows; ++r) {
        float2 v = *reinterpret_cast<const float2*>(p + (size_t)r * T_);
        ins_top(ax0, ax1, ax2, v.x);
        ins_bot(an0, an1, an2, v.x);
        ins_top(bx0, bx1, bx2, v.y);
        ins_bot(bn0, bn1, bn2, v.y);
    }

    const float inv3 = 1.0f / 3.0f;
    size_t o    = (size_t)b * NB * T_ + (size_t)band * T_ + (size_t)tg * VEC;
    size_t voff = (size_t)B_ * NB * T_;

    float2 pk = make_float2((ax0 + ax1 + ax2) * inv3, (bx0 + bx1 + bx2) * inv3);
    float2 vl = make_float2((an0 + an1 + an2) * inv3, (bn0 + bn1 + bn2) * inv3);
    *reinterpret_cast<float2*>(out + o)        = pk;   // peaks
    *reinterpret_cast<float2*>(out + voff + o) = vl;   // valleys
}

extern "C" void kernel_launch(void* const* d_in, const int* in_sizes, int n_in,
                              void* d_out, int out_size, void* d_ws, size_t ws_size,
                              hipStream_t stream) {
    const float* in = (const float*)d_in[0];
    float* out = (float*)d_out;

    int total = B_ * NB * TG;                 // 192000 threads
    int block = 256;
    int grid  = (total + block - 1) / block;  // 750 blocks
    scp_kernel<<<grid, block, 0, stream>>>(in, out);
}